// Round 6
// baseline (1837.278 us; speedup 1.0000x reference)
//
#include <hip/hip_runtime.h>
#include <math.h>

typedef float f32x4 __attribute__((ext_vector_type(4)));
typedef __bf16 bf16x8 __attribute__((ext_vector_type(8)));

#define LRELU_ALPHA 0.2f

// ---------- bf16 split helpers ----------
static __device__ __forceinline__ unsigned short f2b(float f) {
    __bf16 h = (__bf16)f;
    return __builtin_bit_cast(unsigned short, h);
}
static __device__ __forceinline__ float b2f(unsigned short s) {
    unsigned int u = ((unsigned int)s) << 16;
    return __builtin_bit_cast(float, u);
}
static __device__ __forceinline__ void dsplit(float f, unsigned short& h, unsigned short& l) {
    h = f2b(f);
    l = f2b(f - b2f(h));   // exact residual then RNE -> ~2^-18 total
}
static __device__ __forceinline__ float ulo(unsigned int u) { return __builtin_bit_cast(float, u << 16); }
static __device__ __forceinline__ float uhi(unsigned int u) { return __builtin_bit_cast(float, u & 0xFFFF0000u); }

// ------------------------- CSR build -------------------------
__global__ void edge_count(const int* __restrict__ rows, int* __restrict__ cnt, int E) {
    int i = blockIdx.x * 256 + threadIdx.x;
    if (i < E) atomicAdd(&cnt[rows[i]], 1);
}

__global__ __launch_bounds__(512) void scan1(const int* __restrict__ in, int* __restrict__ out,
                                             int* __restrict__ bsum, int ncnt, int nout) {
    __shared__ int s[512];
    int t = threadIdx.x;
    int i = blockIdx.x * 512 + t;
    int v = (i < ncnt) ? in[i] : 0;
    s[t] = v; __syncthreads();
    for (int o = 1; o < 512; o <<= 1) {
        int u = (t >= o) ? s[t - o] : 0;
        __syncthreads();
        s[t] += u;
        __syncthreads();
    }
    if (i < nout) out[i] = s[t] - v;
    if (t == 511) bsum[blockIdx.x] = s[511];
}

__global__ void scan2(int* __restrict__ b, int nb) {
    __shared__ int s[256];
    int t = threadIdx.x;
    int v = (t < nb) ? b[t] : 0;
    s[t] = v; __syncthreads();
    for (int o = 1; o < 256; o <<= 1) {
        int u = (t >= o) ? s[t - o] : 0;
        __syncthreads();
        s[t] += u;
        __syncthreads();
    }
    if (t < nb) b[t] = s[t] - v;
}

__global__ __launch_bounds__(512) void scan3(int* __restrict__ out, const int* __restrict__ bsum, int nout) {
    int i = blockIdx.x * 512 + threadIdx.x;
    if (i < nout) out[i] += bsum[blockIdx.x];
}

__global__ void edge_fill(const int* __restrict__ rows, const int* __restrict__ cols,
                          const float* __restrict__ vals, int* __restrict__ cur,
                          int* __restrict__ ocol, float* __restrict__ oval, int E) {
    int i = blockIdx.x * 256 + threadIdx.x;
    if (i < E) {
        int r = rows[i];
        int p = atomicAdd(&cur[r], 1);
        ocol[p] = cols[i];
        oval[p] = vals[i];
    }
}

// ------------- W -> MFMA B-fragment order, bf16 hi/lo (Dekker) -------------
// o = ((kh*8 + nc)*64 + lane)*8 + j ; col = nc*16+(lane&15); k = kh*32+(lane>>4)*8+j
__global__ void prep_frag(const float* __restrict__ W, unsigned short* __restrict__ Fh,
                          unsigned short* __restrict__ Fl, int K) {
    int o = blockIdx.x * 256 + threadIdx.x;
    if (o >= K * 128) return;
    int j = o & 7;
    int lane = (o >> 3) & 63;
    int blk = o >> 9;
    int nc = blk & 7, kh = blk >> 3;
    int col = nc * 16 + (lane & 15);
    int k = kh * 32 + (lane >> 4) * 8 + j;
    unsigned short h, l;
    dsplit(W[k * 128 + col], h, l);
    Fh[o] = h; Fl[o] = l;
}

// ------------------- SpMM (single plane, 512B pair-unit rows) + bias + LeakyReLU -------------------
__global__ __launch_bounds__(256) void spmm1(const int* __restrict__ ptr, const int* __restrict__ cols,
                                             const float* __restrict__ vals, const char* __restrict__ xb,
                                             const float* __restrict__ bias, char* __restrict__ ob, int nrows) {
    int w = (blockIdx.x << 2) + (threadIdx.x >> 6);
    if (w >= nrows) return;
    int lane = threadIdx.x & 63;
    int loff = lane * 8;
    int s = ptr[w], e = ptr[w + 1];
    float ax = 0.f, ay = 0.f;
    int i = s;
    for (; i + 3 < e; i += 4) {
        int c0 = cols[i], c1 = cols[i + 1], c2 = cols[i + 2], c3 = cols[i + 3];
        float v0 = vals[i], v1 = vals[i + 1], v2 = vals[i + 2], v3 = vals[i + 3];
        uint2 u0 = *(const uint2*)(xb + (size_t)c0 * 512 + loff);
        uint2 u1 = *(const uint2*)(xb + (size_t)c1 * 512 + loff);
        uint2 u2 = *(const uint2*)(xb + (size_t)c2 * 512 + loff);
        uint2 u3 = *(const uint2*)(xb + (size_t)c3 * 512 + loff);
        ax += v0 * (ulo(u0.x) + ulo(u0.y)) + v1 * (ulo(u1.x) + ulo(u1.y))
            + v2 * (ulo(u2.x) + ulo(u2.y)) + v3 * (ulo(u3.x) + ulo(u3.y));
        ay += v0 * (uhi(u0.x) + uhi(u0.y)) + v1 * (uhi(u1.x) + uhi(u1.y))
            + v2 * (uhi(u2.x) + uhi(u2.y)) + v3 * (uhi(u3.x) + uhi(u3.y));
    }
    for (; i < e; i++) {
        int c = cols[i]; float v = vals[i];
        uint2 u = *(const uint2*)(xb + (size_t)c * 512 + loff);
        ax += v * (ulo(u.x) + ulo(u.y));
        ay += v * (uhi(u.x) + uhi(u.y));
    }
    float2 b2 = ((const float2*)bias)[lane];
    ax += b2.x; ay += b2.y;
    ax = ax >= 0.f ? ax : LRELU_ALPHA * ax;
    ay = ay >= 0.f ? ay : LRELU_ALPHA * ay;
    unsigned short h0, l0, h1, l1;
    dsplit(ax, h0, l0); dsplit(ay, h1, l1);
    *(uint2*)(ob + (size_t)w * 512 + loff) =
        make_uint2((unsigned)h0 | ((unsigned)h1 << 16), (unsigned)l0 | ((unsigned)l1 << 16));
}

// ------------------- SpMM pair (m & s planes, 1024B rows) -------------------
__global__ __launch_bounds__(256) void spmm2(const int* __restrict__ ptr, const int* __restrict__ cols,
                                             const float* __restrict__ vals, const char* __restrict__ xb,
                                             const float* __restrict__ bm, const float* __restrict__ bs,
                                             char* __restrict__ ob, int nrows) {
    int w = (blockIdx.x << 2) + (threadIdx.x >> 6);
    if (w >= nrows) return;
    int lane = threadIdx.x & 63;
    int loff = lane * 8;
    int s = ptr[w], e = ptr[w + 1];
    float mx = 0.f, my = 0.f, sx = 0.f, sy = 0.f;
    int i = s;
    for (; i + 1 < e; i += 2) {
        int c0 = cols[i], c1 = cols[i + 1];
        float v0 = vals[i], v1 = vals[i + 1];
        const char* p0 = xb + (size_t)c0 * 1024 + loff;
        const char* p1 = xb + (size_t)c1 * 1024 + loff;
        uint2 m0 = *(const uint2*)p0, s0 = *(const uint2*)(p0 + 512);
        uint2 m1 = *(const uint2*)p1, s1 = *(const uint2*)(p1 + 512);
        mx += v0 * (ulo(m0.x) + ulo(m0.y)) + v1 * (ulo(m1.x) + ulo(m1.y));
        my += v0 * (uhi(m0.x) + uhi(m0.y)) + v1 * (uhi(m1.x) + uhi(m1.y));
        sx += v0 * (ulo(s0.x) + ulo(s0.y)) + v1 * (ulo(s1.x) + ulo(s1.y));
        sy += v0 * (uhi(s0.x) + uhi(s0.y)) + v1 * (uhi(s1.x) + uhi(s1.y));
    }
    for (; i < e; i++) {
        int c = cols[i]; float v = vals[i];
        const char* p = xb + (size_t)c * 1024 + loff;
        uint2 m0 = *(const uint2*)p, s0 = *(const uint2*)(p + 512);
        mx += v * (ulo(m0.x) + ulo(m0.y));
        my += v * (uhi(m0.x) + uhi(m0.y));
        sx += v * (ulo(s0.x) + ulo(s0.y));
        sy += v * (uhi(s0.x) + uhi(s0.y));
    }
    float2 bm2 = ((const float2*)bm)[lane];
    float2 bs2 = ((const float2*)bs)[lane];
    mx += bm2.x; my += bm2.y; sx += bs2.x; sy += bs2.y;
    mx = mx >= 0.f ? mx : LRELU_ALPHA * mx;
    my = my >= 0.f ? my : LRELU_ALPHA * my;
    sx = sx >= 0.f ? sx : LRELU_ALPHA * sx;
    sy = sy >= 0.f ? sy : LRELU_ALPHA * sy;
    unsigned short h0, l0, h1, l1;
    char* po = ob + (size_t)w * 1024 + loff;
    dsplit(mx, h0, l0); dsplit(my, h1, l1);
    *(uint2*)po = make_uint2((unsigned)h0 | ((unsigned)h1 << 16), (unsigned)l0 | ((unsigned)l1 << 16));
    dsplit(sx, h0, l0); dsplit(sy, h1, l1);
    *(uint2*)(po + 512) = make_uint2((unsigned)h0 | ((unsigned)h1 << 16), (unsigned)l0 | ((unsigned)l1 << 16));
}

// ---------------- MFMA GEMM helpers ----------------
static __device__ __forceinline__ void load32(const char* p, bf16x8& h8, bf16x8& l8) {
    uint4 u0 = *(const uint4*)p;
    uint4 u1 = *(const uint4*)(p + 16);
    union { unsigned int u[4]; bf16x8 v; } H, L;
    H.u[0] = u0.x; H.u[1] = u0.z; H.u[2] = u1.x; H.u[3] = u1.z;
    L.u[0] = u0.y; L.u[1] = u0.w; L.u[2] = u1.y; L.u[3] = u1.w;
    h8 = H.v; l8 = L.v;
}
static __device__ __forceinline__ void split8(float4 f0, float4 f1, bf16x8& h8, bf16x8& l8) {
    float fv[8] = {f0.x, f0.y, f0.z, f0.w, f1.x, f1.y, f1.z, f1.w};
#pragma unroll
    for (int j = 0; j < 8; j++) {
        __bf16 h = (__bf16)fv[j];
        h8[j] = h;
        l8[j] = (__bf16)(fv[j] - (float)h);
    }
}
static __device__ __forceinline__ f32x4 acc3(f32x4 a, bf16x8 xh, bf16x8 xl, bf16x8 bh, bf16x8 bl) {
    a = __builtin_amdgcn_mfma_f32_16x16x32_bf16(xh, bh, a, 0, 0, 0);
    a = __builtin_amdgcn_mfma_f32_16x16x32_bf16(xh, bl, a, 0, 0, 0);
    a = __builtin_amdgcn_mfma_f32_16x16x32_bf16(xl, bh, a, 0, 0, 0);
    return a;
}

// MODE 0=GC1: A = A2f raw f32 [M][128]; one W; out pair-unit 512B rows
// MODE 1=DUAL: A = A1 pair-unit 512B rows; two W share A; out pair-unit 1024B rows (m@0, s@512)
// MODE 2=FINAL: K=256: kh<4 A1 pair-unit 1024B rows (m@0,s@512); kh>=4 A2f raw f32 (fea);
//               bias + reparam epilogue, f32 out rows
// Epilogue always stages through per-wave LDS and stores full contiguous rows.
template <int MODE>
__global__ __launch_bounds__(256) void gemm_u(const char* __restrict__ A1, const float* __restrict__ A2f,
                                              const unsigned short* __restrict__ F1h, const unsigned short* __restrict__ F1l,
                                              const unsigned short* __restrict__ F2h, const unsigned short* __restrict__ F2l,
                                              const float* __restrict__ bias1, const float* __restrict__ bias2,
                                              const float* __restrict__ noise, float* __restrict__ out,
                                              char* __restrict__ outb, int M) {
    __shared__ float xpose[4][2080];            // 4 waves x 16 rows x 130 (pad) f32
    const int t = threadIdx.x;
    const int lane = t & 63;
    const int w = t >> 6;
    const int l15 = lane & 15, l4 = lane >> 4;
    const int rowW = blockIdx.x * 64 + w * 16;
    int ar = rowW + l15;
    const int arc = (ar < M) ? ar : (M - 1);    // clamped A-row (garbage rows never stored)
    float* lds = xpose[w];

    f32x4 accM[8] = {};
    f32x4 accS[8] = {};

    constexpr int KPH = (MODE == 2) ? 8 : 4;
#pragma unroll
    for (int kh = 0; kh < KPH; kh++) {
        const int kk = (kh & 3) * 32 + l4 * 8;
        bf16x8 amh, aml, xsh, xsl;
        if constexpr (MODE == 0) {
            const float* p = A2f + (size_t)arc * 128 + kk;
            split8(*(const float4*)p, *(const float4*)(p + 4), amh, aml);
            xsh = amh; xsl = aml;
        } else if constexpr (MODE == 1) {
            load32(A1 + (size_t)arc * 512 + (size_t)kk * 4, amh, aml);
            xsh = amh; xsl = aml;
        } else {
            if (kh < 4) {
                load32(A1 + (size_t)arc * 1024 + (size_t)kk * 4, amh, aml);
                load32(A1 + (size_t)arc * 1024 + 512 + (size_t)kk * 4, xsh, xsl);
            } else {
                const float* p = A2f + (size_t)arc * 128 + kk;
                split8(*(const float4*)p, *(const float4*)(p + 4), amh, aml);
                xsh = amh; xsl = aml;
            }
        }
        const unsigned short* f1h = F1h + (size_t)kh * 4096;
        const unsigned short* f1l = F1l + (size_t)kh * 4096;
        const unsigned short* f2h = F2h + (size_t)kh * 4096;
        const unsigned short* f2l = F2l + (size_t)kh * 4096;
#pragma unroll
        for (int nc = 0; nc < 8; nc++) {
            bf16x8 b1h = *(const bf16x8*)(f1h + nc * 512 + lane * 8);
            bf16x8 b1l = *(const bf16x8*)(f1l + nc * 512 + lane * 8);
            accM[nc] = acc3(accM[nc], amh, aml, b1h, b1l);
            if constexpr (MODE >= 1) {
                bf16x8 b2h = *(const bf16x8*)(f2h + nc * 512 + lane * 8);
                bf16x8 b2l = *(const bf16x8*)(f2l + nc * 512 + lane * 8);
                accS[nc] = acc3(accS[nc], xsh, xsl, b2h, b2l);
            }
        }
    }

    // epilogue: C/D layout col = lane&15, row = (lane>>4)*4 + j; stage in per-wave LDS,
    // then store full contiguous rows (8B/lane x 64 lanes = whole cache lines, no RMW).
    if constexpr (MODE == 2) {
#pragma unroll
        for (int nc = 0; nc < 8; nc++) {
            int c = nc * 16 + l15;
            float b1 = bias1[c], b2v = bias2[c];
#pragma unroll
            for (int j = 0; j < 4; j++) {
                int r = rowW + l4 * 4 + j;
                int rc = (r < M) ? r : (M - 1);
                float mean = accM[nc][j] + b1;
                float ls = accS[nc][j] + b2v;
                float sp = ls > 0.f ? ls + log1pf(expf(-ls)) : log1pf(expf(ls));
                float sg = expf(0.1f + 0.9f * sp);
                lds[(l4 * 4 + j) * 130 + c] = noise[(size_t)rc * 128 + c] * sg + mean;
            }
        }
#pragma unroll
        for (int p = 0; p < 16; p++) {
            int r = rowW + p;
            if (r < M) {
                float2 f = *(const float2*)&lds[p * 130 + lane * 2];
                *(float2*)(out + (size_t)r * 128 + lane * 2) = f;
            }
        }
    } else {
        const size_t rstride = (MODE == 0) ? 512 : 1024;
        // plane M
#pragma unroll
        for (int nc = 0; nc < 8; nc++)
#pragma unroll
            for (int j = 0; j < 4; j++)
                lds[(l4 * 4 + j) * 130 + nc * 16 + l15] = accM[nc][j];
#pragma unroll
        for (int p = 0; p < 16; p++) {
            int r = rowW + p;
            if (r < M) {
                float2 f = *(const float2*)&lds[p * 130 + lane * 2];
                unsigned short h0, l0, h1, l1;
                dsplit(f.x, h0, l0); dsplit(f.y, h1, l1);
                *(uint2*)(outb + (size_t)r * rstride + lane * 8) =
                    make_uint2((unsigned)h0 | ((unsigned)h1 << 16), (unsigned)l0 | ((unsigned)l1 << 16));
            }
        }
        if constexpr (MODE == 1) {
            // plane S reuses the same per-wave LDS region (compiler orders LDS ops)
#pragma unroll
            for (int nc = 0; nc < 8; nc++)
#pragma unroll
                for (int j = 0; j < 4; j++)
                    lds[(l4 * 4 + j) * 130 + nc * 16 + l15] = accS[nc][j];
#pragma unroll
            for (int p = 0; p < 16; p++) {
                int r = rowW + p;
                if (r < M) {
                    float2 f = *(const float2*)&lds[p * 130 + lane * 2];
                    unsigned short h0, l0, h1, l1;
                    dsplit(f.x, h0, l0); dsplit(f.y, h1, l1);
                    *(uint2*)(outb + (size_t)r * rstride + 512 + lane * 8) =
                        make_uint2((unsigned)h0 | ((unsigned)h1 << 16), (unsigned)l0 | ((unsigned)l1 << 16));
                }
            }
        }
    }
}

// ------------------------- launcher -------------------------
extern "C" void kernel_launch(void* const* d_in, const int* in_sizes, int n_in,
                              void* d_out, int out_size, void* d_ws, size_t ws_size,
                              hipStream_t stream) {
    const float* ufea    = (const float*)d_in[0];
    const float* vfea    = (const float*)d_in[1];
    const int*   uv_rows = (const int*)d_in[2];
    const int*   uv_cols = (const int*)d_in[3];
    const float* uv_vals = (const float*)d_in[4];
    const int*   vu_rows = (const int*)d_in[5];
    const int*   vu_cols = (const int*)d_in[6];
    const float* vu_vals = (const float*)d_in[7];
    const float* noise_u = (const float*)d_in[8];
    const float* noise_v = (const float*)d_in[9];
    const float* gc1_W  = (const float*)d_in[10];
    const float* gc1_b  = (const float*)d_in[11];
    const float* gc3m_W = (const float*)d_in[12];
    const float* gc3m_b = (const float*)d_in[13];
    const float* gc3s_W = (const float*)d_in[14];
    const float* gc3s_b = (const float*)d_in[15];
    const float* um_W = (const float*)d_in[16];
    const float* um_b = (const float*)d_in[17];
    const float* us_W = (const float*)d_in[18];
    const float* us_b = (const float*)d_in[19];
    const float* im_W = (const float*)d_in[20];
    const float* im_b = (const float*)d_in[21];
    const float* is_W = (const float*)d_in[22];
    const float* is_b = (const float*)d_in[23];

    const int H  = in_sizes[11];          // 128
    const int D  = in_sizes[10] / H;      // 128
    const int NU = in_sizes[0] / D;       // 100000
    const int NV = in_sizes[1] / D;       // 50000
    const int E  = in_sizes[2];           // 1600000

    char* ws = (char*)d_ws;
    size_t off = 0;
    auto alloc = [&](size_t bytes) -> char* {
        char* p = ws + off;
        off = (off + bytes + 255) & ~(size_t)255;
        return p;
    };
    unsigned short* f_gc1_h  = (unsigned short*)alloc(128 * 128 * 2);
    unsigned short* f_gc1_l  = (unsigned short*)alloc(128 * 128 * 2);
    unsigned short* f_gc3m_h = (unsigned short*)alloc(128 * 128 * 2);
    unsigned short* f_gc3m_l = (unsigned short*)alloc(128 * 128 * 2);
    unsigned short* f_gc3s_h = (unsigned short*)alloc(128 * 128 * 2);
    unsigned short* f_gc3s_l = (unsigned short*)alloc(128 * 128 * 2);
    unsigned short* f_um_h = (unsigned short*)alloc(256 * 128 * 2);
    unsigned short* f_um_l = (unsigned short*)alloc(256 * 128 * 2);
    unsigned short* f_us_h = (unsigned short*)alloc(256 * 128 * 2);
    unsigned short* f_us_l = (unsigned short*)alloc(256 * 128 * 2);
    unsigned short* f_im_h = (unsigned short*)alloc(256 * 128 * 2);
    unsigned short* f_im_l = (unsigned short*)alloc(256 * 128 * 2);
    unsigned short* f_is_h = (unsigned short*)alloc(256 * 128 * 2);
    unsigned short* f_is_l = (unsigned short*)alloc(256 * 128 * 2);
    int*   ptr_uv = (int*)alloc((size_t)(NU + 1) * 4);
    int*   cur_uv = (int*)alloc((size_t)NU * 4);
    int*   col_uv = (int*)alloc((size_t)E * 4);
    float* val_uv = (float*)alloc((size_t)E * 4);
    int*   ptr_vu = (int*)alloc((size_t)(NV + 1) * 4);
    int*   cur_vu = (int*)alloc((size_t)NV * 4);
    int*   col_vu = (int*)alloc((size_t)E * 4);
    float* val_vu = (float*)alloc((size_t)E * 4);
    int*   bsum   = (int*)alloc(1024 * 4);
    char* P = alloc((size_t)NU * 1024);   // hop_u (user), dual_u (item)
    char* Q = alloc((size_t)NU * 512);    // gc1_u / dual_v / ho_u / hop_v
    char* R = alloc((size_t)NV * 512);    // user_ho / sup_v
    // total ~207 MB (round-5's 309 MB crashed; round-2's 131 MB was fine)

    float* outU = (float*)d_out;
    float* outI = outU + (size_t)NU * H;

    const int eb = (E + 255) / 256;
    const int nbU = (NU + 1 + 511) / 512;
    const int nbV = (NV + 1 + 511) / 512;
    const int gU = (NU + 63) / 64, gV = (NV + 63) / 64;
    const int sU = (NU + 3) / 4, sV = (NV + 3) / 4;

    // ---- CSR build ----
    hipMemsetAsync(cur_uv, 0, (size_t)NU * 4, stream);
    hipMemsetAsync(cur_vu, 0, (size_t)NV * 4, stream);
    edge_count<<<eb, 256, 0, stream>>>(uv_rows, cur_uv, E);
    edge_count<<<eb, 256, 0, stream>>>(vu_rows, cur_vu, E);
    scan1<<<nbU, 512, 0, stream>>>(cur_uv, ptr_uv, bsum, NU, NU + 1);
    scan2<<<1, 256, 0, stream>>>(bsum, nbU);
    scan3<<<nbU, 512, 0, stream>>>(ptr_uv, bsum, NU + 1);
    scan1<<<nbV, 512, 0, stream>>>(cur_vu, ptr_vu, bsum, NV, NV + 1);
    scan2<<<1, 256, 0, stream>>>(bsum, nbV);
    scan3<<<nbV, 512, 0, stream>>>(ptr_vu, bsum, NV + 1);
    hipMemcpyAsync(cur_uv, ptr_uv, (size_t)NU * 4, hipMemcpyDeviceToDevice, stream);
    hipMemcpyAsync(cur_vu, ptr_vu, (size_t)NV * 4, hipMemcpyDeviceToDevice, stream);
    edge_fill<<<eb, 256, 0, stream>>>(uv_rows, uv_cols, uv_vals, cur_uv, col_uv, val_uv, E);
    edge_fill<<<eb, 256, 0, stream>>>(vu_rows, vu_cols, vu_vals, cur_vu, col_vu, val_vu, E);

    // ---- weight fragments ----
    prep_frag<<<64, 256, 0, stream>>>(gc1_W, f_gc1_h, f_gc1_l, 128);
    prep_frag<<<64, 256, 0, stream>>>(gc3m_W, f_gc3m_h, f_gc3m_l, 128);
    prep_frag<<<64, 256, 0, stream>>>(gc3s_W, f_gc3s_h, f_gc3s_l, 128);
    prep_frag<<<128, 256, 0, stream>>>(um_W, f_um_h, f_um_l, 256);
    prep_frag<<<128, 256, 0, stream>>>(us_W, f_us_h, f_us_l, 256);
    prep_frag<<<128, 256, 0, stream>>>(im_W, f_im_h, f_im_l, 256);
    prep_frag<<<128, 256, 0, stream>>>(is_W, f_is_h, f_is_l, 256);

    // ---- user path ----
    gemm_u<0><<<gU, 256, 0, stream>>>(nullptr, ufea, f_gc1_h, f_gc1_l, nullptr, nullptr,
                                      nullptr, nullptr, nullptr, nullptr, Q, NU);          // gc1_u -> Q
    spmm1<<<sV, 256, 0, stream>>>(ptr_vu, col_vu, val_vu, Q, gc1_b, R, NV);                // user_ho -> R
    gemm_u<1><<<gV, 256, 0, stream>>>(R, nullptr, f_gc3m_h, f_gc3m_l, f_gc3s_h, f_gc3s_l,
                                      nullptr, nullptr, nullptr, nullptr, Q, NV);          // dual_v -> Q
    spmm2<<<sU, 256, 0, stream>>>(ptr_uv, col_uv, val_uv, Q, gc3m_b, gc3s_b, P, NU);       // hop_u -> P
    gemm_u<2><<<gU, 256, 0, stream>>>(P, ufea, f_um_h, f_um_l, f_us_h, f_us_l,
                                      um_b, us_b, noise_u, outU, nullptr, NU);             // user_z

    // ---- item path ----
    gemm_u<0><<<gV, 256, 0, stream>>>(nullptr, vfea, f_gc1_h, f_gc1_l, nullptr, nullptr,
                                      nullptr, nullptr, nullptr, nullptr, R, NV);          // sup_v -> R
    spmm1<<<sU, 256, 0, stream>>>(ptr_uv, col_uv, val_uv, R, gc1_b, Q, NU);                // item_ho -> Q
    gemm_u<1><<<gU, 256, 0, stream>>>(Q, nullptr, f_gc3m_h, f_gc3m_l, f_gc3s_h, f_gc3s_l,
                                      nullptr, nullptr, nullptr, nullptr, P, NU);          // dual_u -> P
    spmm2<<<sV, 256, 0, stream>>>(ptr_vu, col_vu, val_vu, P, gc3m_b, gc3s_b, Q, NV);       // hop_v -> Q
    gemm_u<2><<<gV, 256, 0, stream>>>(Q, vfea, f_im_h, f_im_l, f_is_h, f_is_l,
                                      im_b, is_b, noise_v, outI, nullptr, NV);             // item_z

    (void)n_in; (void)out_size; (void)ws_size;
}